// Round 3
// baseline (772.662 us; speedup 1.0000x reference)
//
#include <hip/hip_runtime.h>

// NodeBlock: agg = segment_sum(edges[1.6M,64], recv -> 50000 nodes)
//            X = [agg | nodes] (globals folded into bias)  (50000 x 192) bf16
//            out = relu(X@W1[:192]+b1') @ W2 + b2          (f32, 50000 x 128)
//
// R22: bucket-direct. NPB = MT = 64 -> bucket == M-tile. Fused kernel streams
// its bucket's sorted1 segment, gathers edge rows (random 256B, the HBM floor)
// and accumulates straight into an LDS f32 tile via ds_add_f32. Eliminates
// regroup kernel, eidcsr, and the per-node CSR latency chain that capped
// R20/R21's gather at ~3.3 TB/s. MLP phases identical to R21 (proven).
// aggF stride 65 f32 (odd dword stride -> atomic bank spread). LDS pool 60KB:
// Xs[0,25.6K) | aggF/Hs overlap [25.6K,61.4K) (phase-disjoint) -> 2 blocks/CU.

typedef __bf16 bf16x8 __attribute__((ext_vector_type(8)));
typedef __bf16 bf16x4 __attribute__((ext_vector_type(4)));
typedef __bf16 bf16x2 __attribute__((ext_vector_type(2)));
typedef float f32x4 __attribute__((ext_vector_type(4)));
typedef int i32x4 __attribute__((ext_vector_type(4)));

#define EDGE_DIM 64
#define NODE_DIM 128
#define XDIM 192     // agg(64) | nodes(128); globals folded into bias
#define XPAD 200     // Xs row stride bf16 (400B, 16B-aligned rows)
#define HID_DIM 256
#define OUT_DIM 128
#define MT 64        // M-tile == bucket size
#define NBUCKET 782  // ceil(50000/64); local < 64 (6 bits)
#define EPB 4096     // edges per hist/scatter block (256 thr x 16)
#define HPAD 280     // Hs row stride (bf16)
#define APAD 65      // aggF row stride (f32, odd dword stride)

// ---------------- K1: weight prep (+bias fold) + per-block bucket histogram --
__global__ __launch_bounds__(256) void prep_hist_kernel(
    const float* __restrict__ W1, const float* __restrict__ b1,
    const float* __restrict__ W2, const float* __restrict__ glob,
    __bf16* __restrict__ W1T, float* __restrict__ b1f, __bf16* __restrict__ W2T,
    const int* __restrict__ recv, int* __restrict__ bh, int n_edges) {
  const int b = blockIdx.x, t = threadIdx.x;
  if (b < HID_DIM) {
    if (t < XDIM) {
      W1T[b * XDIM + t] = (__bf16)W1[t * HID_DIM + b];
    } else {
      // threads 192..255 == wave 3: fold globals into bias (f32 exact)
      float p = glob[t - XDIM] * W1[t * HID_DIM + b];
      for (int off = 32; off; off >>= 1) p += __shfl_xor(p, off, 64);
      if (t == XDIM) b1f[b] = b1[b] + p;
    }
    return;
  }
  if (b < HID_DIM + OUT_DIM) {
    int nn = b - HID_DIM;
    W2T[nn * HID_DIM + t] = (__bf16)W2[t * OUT_DIM + nn];
    return;
  }
  const int hb = b - (HID_DIM + OUT_DIM);
  __shared__ int h[NBUCKET];
  for (int k = t; k < NBUCKET; k += 256) h[k] = 0;
  __syncthreads();
  const int i0 = hb * EPB + t * 16;
  if (i0 + 16 <= n_edges) {
#pragma unroll
    for (int c = 0; c < 4; ++c) {
      i32x4 r4 = *(const i32x4*)(recv + i0 + c * 4);
      atomicAdd(&h[r4.x >> 6], 1);
      atomicAdd(&h[r4.y >> 6], 1);
      atomicAdd(&h[r4.z >> 6], 1);
      atomicAdd(&h[r4.w >> 6], 1);
    }
  } else {
    for (int j = 0; j < 16; ++j)
      if (i0 + j < n_edges) atomicAdd(&h[recv[i0 + j] >> 6], 1);
  }
  __syncthreads();
  for (int k = t; k < NBUCKET; k += 256) bh[(size_t)hb * NBUCKET + k] = h[k];
}

// ---------------- K2a: WAVE-PARALLEL column scan (one wave per bucket) ------
__global__ __launch_bounds__(256) void col_scan_kernel(
    int* __restrict__ bh, int* __restrict__ tot, int nbh) {
  const int bucket = (blockIdx.x * 256 + threadIdx.x) >> 6;
  const int lane = threadIdx.x & 63;
  const bool bok = bucket < NBUCKET;
  int running = 0;
  for (int c = 0; c < nbh; c += 64) {
    const int k = c + lane;
    int v = (bok && k < nbh) ? bh[(size_t)k * NBUCKET + bucket] : 0;
    int incl = v;
    for (int off = 1; off < 64; off <<= 1) {
      int y = __shfl_up(incl, off, 64);
      if (lane >= off) incl += y;
    }
    if (bok && k < nbh) bh[(size_t)k * NBUCKET + bucket] = running + incl - v;
    running += __shfl(incl, 63, 64);
  }
  if (bok && lane == 0) tot[bucket] = running;
}

// ---------------- K2b: base scan over 782 totals (1 block of 1024) ----------
__global__ __launch_bounds__(1024) void base_scan_kernel(const int* __restrict__ tot,
                                                         int* __restrict__ base) {
  const int b = threadIdx.x;
  int v = (b < NBUCKET) ? tot[b] : 0;
  __shared__ int sums[1024];
  sums[b] = v;
  __syncthreads();
  for (int off = 1; off < 1024; off <<= 1) {
    int y = (b >= off) ? sums[b - off] : 0;
    __syncthreads();
    sums[b] += y;
    __syncthreads();
  }
  if (b < NBUCKET) base[b] = sums[b] - v;  // exclusive
  if (b == NBUCKET - 1) base[NBUCKET] = sums[b];
}

// ---------------- K3: scatter packed (eid<<6)|local, LDS cursors ------------
__global__ __launch_bounds__(256) void scatter_kernel(
    const int* __restrict__ recv, const int* __restrict__ off,
    const int* __restrict__ base, int* __restrict__ sorted1, int n_edges) {
  const int kb = blockIdx.x, t = threadIdx.x;
  __shared__ int cur[NBUCKET];
  for (int k = t; k < NBUCKET; k += 256)
    cur[k] = base[k] + off[(size_t)kb * NBUCKET + k];
  __syncthreads();
  const int i0 = kb * EPB + t * 16;
  if (i0 + 16 <= n_edges) {
#pragma unroll
    for (int c = 0; c < 4; ++c) {
      i32x4 r4 = *(const i32x4*)(recv + i0 + c * 4);
      const int e0 = i0 + c * 4;
      int bk, p;
      bk = r4.x >> 6; p = atomicAdd(&cur[bk], 1);
      sorted1[p] = ((e0 + 0) << 6) | (r4.x & 63);
      bk = r4.y >> 6; p = atomicAdd(&cur[bk], 1);
      sorted1[p] = ((e0 + 1) << 6) | (r4.y & 63);
      bk = r4.z >> 6; p = atomicAdd(&cur[bk], 1);
      sorted1[p] = ((e0 + 2) << 6) | (r4.z & 63);
      bk = r4.w >> 6; p = atomicAdd(&cur[bk], 1);
      sorted1[p] = ((e0 + 3) << 6) | (r4.w & 63);
    }
  } else {
    for (int j = 0; j < 16; ++j) {
      const int i = i0 + j;
      if (i < n_edges) {
        int r = recv[i];
        int bk = r >> 6;
        int p = atomicAdd(&cur[bk], 1);
        sorted1[p] = (i << 6) | (r & 63);
      }
    }
  }
}

// ---------------- K4: FUSED bucket gather (LDS f32 atomics) -> MLP ----------
#define NTLOAD(i) __builtin_nontemporal_load((const f32x4*)(edges + (size_t)(i) * EDGE_DIM + l15 * 4))

__global__ __launch_bounds__(512, 4) void fused_kernel(
    const float* __restrict__ edges, const int* __restrict__ sorted1,
    const int* __restrict__ base, const float* __restrict__ nodes,
    const __bf16* __restrict__ W1T, const float* __restrict__ b1f,
    const __bf16* __restrict__ W2T, const float* __restrict__ b2,
    float* __restrict__ out, int M) {
  __shared__ __align__(16) char pool[61440];
  __bf16(*Xs)[XPAD] = (__bf16(*)[XPAD])pool;             // [64][200] bf16, 25600B
  float(*aggF)[APAD] = (float(*)[APAD])(pool + 25600);   // [65][65] f32, 16900B
  __bf16(*Hs)[HPAD] = (__bf16(*)[HPAD])(pool + 25600);   // [64][280] bf16, 35840B (overlaps aggF)

  const int wave = threadIdx.x >> 6;  // 0..7
  const int lane = threadIdx.x & 63;
  const int q = lane >> 4;
  const int l15 = lane & 15;
  const int lk = q;
  const int Mbase0 = blockIdx.x * MT;

  // ---- 0: zero aggF (65 rows incl. trash row 64) --------------------------
  for (int t = threadIdx.x; t < 65 * APAD; t += 512) ((float*)aggF)[t] = 0.f;

  // ---- 1: nodes -> Xs cols 64..191 (independent of aggF) ------------------
  for (int r = wave * 8; r < wave * 8 + 8; ++r) {
    const int node = Mbase0 + r;
    bf16x2 nb;
    if (node < M) {
      float2 nv = *(const float2*)(nodes + (size_t)node * NODE_DIM + lane * 2);
      nb[0] = (__bf16)nv.x; nb[1] = (__bf16)nv.y;
    } else {
      nb[0] = (__bf16)0.f; nb[1] = (__bf16)0.f;
    }
    *(bf16x2*)(&Xs[r][EDGE_DIM + lane * 2]) = nb;
  }
  __syncthreads();  // aggF zeroed before atomics

  // ---- 2: gather bucket edges, ds_add_f32 into aggF -----------------------
  {
    const int s = base[blockIdx.x], e = base[blockIdx.x + 1];
    const int slot = wave * 4 + q;  // 0..31
    int jj = s + slot;
    int E0, L0, E1, L1, E2, L2, E3, L3, E4, L4, E5, L5, E6, L6, E7, L7;
#define FETCH(i, idx)                                            \
  do {                                                           \
    int _x = (idx);                                              \
    if (_x < e) { int _p = sorted1[_x]; E##i = _p >> 6; L##i = _p & 63; } \
    else { E##i = 0; L##i = 64; }                                \
  } while (0)
    FETCH(0, jj + 0 * 32); FETCH(1, jj + 1 * 32);
    FETCH(2, jj + 2 * 32); FETCH(3, jj + 3 * 32);
    FETCH(4, jj + 4 * 32); FETCH(5, jj + 5 * 32);
    FETCH(6, jj + 6 * 32); FETCH(7, jj + 7 * 32);
    while (jj < e) {
      f32x4 v0 = NTLOAD(E0);
      f32x4 v1 = NTLOAD(E1);
      f32x4 v2 = NTLOAD(E2);
      f32x4 v3 = NTLOAD(E3);
      f32x4 v4 = NTLOAD(E4);
      f32x4 v5 = NTLOAD(E5);
      f32x4 v6 = NTLOAD(E6);
      f32x4 v7 = NTLOAD(E7);
      const int nj = jj + 256;
      int a0 = L0, a1 = L1, a2 = L2, a3 = L3, a4 = L4, a5 = L5, a6 = L6, a7 = L7;
      FETCH(0, nj + 0 * 32); FETCH(1, nj + 1 * 32);
      FETCH(2, nj + 2 * 32); FETCH(3, nj + 3 * 32);
      FETCH(4, nj + 4 * 32); FETCH(5, nj + 5 * 32);
      FETCH(6, nj + 6 * 32); FETCH(7, nj + 7 * 32);
#define ACC(vv, ll)                                   \
  atomicAdd(&aggF[ll][l15 * 4 + 0], vv[0]);           \
  atomicAdd(&aggF[ll][l15 * 4 + 1], vv[1]);           \
  atomicAdd(&aggF[ll][l15 * 4 + 2], vv[2]);           \
  atomicAdd(&aggF[ll][l15 * 4 + 3], vv[3])
      ACC(v0, a0); ACC(v1, a1); ACC(v2, a2); ACC(v3, a3);
      ACC(v4, a4); ACC(v5, a5); ACC(v6, a6); ACC(v7, a7);
#undef ACC
      jj = nj;
    }
#undef FETCH
  }
  __syncthreads();

  // ---- 3: aggF -> Xs cols 0..63 (bf16) ------------------------------------
  for (int t = threadIdx.x; t < 64 * 64; t += 512) {
    const int r = t >> 6, d = t & 63;
    Xs[r][d] = (__bf16)aggF[r][d];
  }
  __syncthreads();

  {  // phase 1: H = relu(Xs @ W1[:192] + b1') -> LDS (K = 192, 6 ks steps)
    bf16x8 B1[2][6];
    float bias1[2];
    const int colbase = wave * 32;
#pragma unroll
    for (int cb = 0; cb < 2; ++cb) {
      const int col = colbase + cb * 16 + l15;
      const __bf16* wrow = W1T + col * XDIM + lk * 8;
#pragma unroll
      for (int ks = 0; ks < 6; ++ks) B1[cb][ks] = *(const bf16x8*)(wrow + ks * 32);
      bias1[cb] = b1f[col];
    }
#pragma unroll
    for (int mb = 0; mb < 4; ++mb) {
      f32x4 acc[2];
#pragma unroll
      for (int cb = 0; cb < 2; ++cb) {
        f32x4 ini = {bias1[cb], bias1[cb], bias1[cb], bias1[cb]};
        acc[cb] = ini;
      }
      const __bf16* xrow = &Xs[mb * 16 + l15][lk * 8];
#pragma unroll
      for (int ks = 0; ks < 6; ++ks) {
        bf16x8 A = *(const bf16x8*)(xrow + ks * 32);
#pragma unroll
        for (int cb = 0; cb < 2; ++cb)
          acc[cb] = __builtin_amdgcn_mfma_f32_16x16x32_bf16(A, B1[cb][ks], acc[cb], 0, 0, 0);
      }
#pragma unroll
      for (int cb = 0; cb < 2; ++cb) {
#pragma unroll
        for (int r = 0; r < 4; ++r) {
          float v = acc[cb][r];
          Hs[mb * 16 + lk * 4 + r][colbase + cb * 16 + l15] = (__bf16)(v > 0.f ? v : 0.f);
        }
      }
    }
  }
  __syncthreads();
  {  // phase 2: out = H @ W2 + b2 (1 colblock of 16 per wave: 8*16 = 128)
    bf16x8 B2[8];
    const int col = wave * 16 + l15;
    const __bf16* wrow = W2T + col * HID_DIM + lk * 8;
#pragma unroll
    for (int ks = 0; ks < 8; ++ks) B2[ks] = *(const bf16x8*)(wrow + ks * 32);
    const float bias2 = b2[col];
#pragma unroll
    for (int mb = 0; mb < 4; ++mb) {
      const int Mbase = Mbase0 + mb * 16;
      f32x4 acc = {bias2, bias2, bias2, bias2};
#pragma unroll
      for (int ks = 0; ks < 8; ++ks) {
        bf16x8 A = *(const bf16x8*)(&Hs[mb * 16 + l15][lk * 8 + ks * 32]);
        acc = __builtin_amdgcn_mfma_f32_16x16x32_bf16(A, B2[ks], acc, 0, 0, 0);
      }
#pragma unroll
      for (int r = 0; r < 4; ++r) {
        const int row = Mbase + lk * 4 + r;
        if (row < M) out[(size_t)row * OUT_DIM + col] = acc[r];
      }
    }
  }
}

extern "C" void kernel_launch(void* const* d_in, const int* in_sizes, int n_in,
                              void* d_out, int out_size, void* d_ws, size_t ws_size,
                              hipStream_t stream) {
  const float* edges    = (const float*)d_in[0];
  const int*   recv     = (const int*)d_in[1];
  const float* nodes    = (const float*)d_in[2];
  const float* globals_ = (const float*)d_in[3];
  const float* W1       = (const float*)d_in[5];
  const float* b1       = (const float*)d_in[6];
  const float* W2       = (const float*)d_in[7];
  const float* b2       = (const float*)d_in[8];

  const int n_edges = in_sizes[0] / EDGE_DIM;  // 1600000
  const int n_nodes = in_sizes[2] / NODE_DIM;  // 50000
  const int NBH = (n_edges + EPB - 1) / EPB;   // 391 hist/scatter blocks
  float* out = (float*)d_out;

  // workspace layout (~8 MB)
  char* ws = (char*)d_ws;
  size_t off = 0;
  int* bh = (int*)(ws + off);      off += (size_t)NBH * NBUCKET * 4;
  off = (off + 255) & ~(size_t)255;
  int* tot = (int*)(ws + off);     off += NBUCKET * 4;
  off = (off + 255) & ~(size_t)255;
  int* base = (int*)(ws + off);    off += (NBUCKET + 1) * 4;
  off = (off + 255) & ~(size_t)255;
  int* sorted1 = (int*)(ws + off); off += (size_t)n_edges * 4;
  off = (off + 255) & ~(size_t)255;
  __bf16* W1T = (__bf16*)(ws + off); off += (size_t)HID_DIM * XDIM * 2;
  off = (off + 255) & ~(size_t)255;
  float* b1f = (float*)(ws + off);  off += HID_DIM * 4;
  off = (off + 255) & ~(size_t)255;
  __bf16* W2T = (__bf16*)(ws + off); off += (size_t)HID_DIM * OUT_DIM * 2;

  prep_hist_kernel<<<HID_DIM + OUT_DIM + NBH, 256, 0, stream>>>(
      W1, b1, W2, globals_, W1T, b1f, W2T, recv, bh, n_edges);
  col_scan_kernel<<<(NBUCKET + 3) / 4, 256, 0, stream>>>(bh, tot, NBH);
  base_scan_kernel<<<1, 1024, 0, stream>>>(tot, base);
  scatter_kernel<<<NBH, 256, 0, stream>>>(recv, bh, base, sorted1, n_edges);
  fused_kernel<<<NBUCKET, 512, 0, stream>>>(
      edges, sorted1, base, nodes, W1T, b1f, W2T, b2, out, n_nodes);
}

// Round 4
// 159.059 us; speedup vs baseline: 4.8577x; 4.8577x over previous
//
#include <hip/hip_runtime.h>

// NodeBlock: agg = segment_sum(edges[1.6M,64], recv -> 50000 nodes)
//            X = [agg | nodes] (globals folded into bias)  (50000 x 192) bf16
//            out = relu(X@W1[:192]+b1') @ W2 + b2          (f32, 50000 x 128)
//
// R23 = R19 split structure (best measured: 168.2 us) + globals-fold.
// Fusion post-mortems: R20 (8 waves/CU) starved gather; R21 (16 waves/CU)
// break-even; R22 (LDS-atomic bucket-direct) collapsed the gather pipeline
// (VGPR=52 -> loads serialized, 765 us). Fusion abandoned per pre-committed
// rule. Globals-fold kept: b1' = b1 + g@W1[192:256] f32-exact in prep;
// X is 192-dim, mlp phase-1 K 256->192.
// R19 ledger: build_x 83 | mlp 40 | scatter+regroup 22 | small+gaps ~23.

typedef __bf16 bf16x8 __attribute__((ext_vector_type(8)));
typedef __bf16 bf16x4 __attribute__((ext_vector_type(4)));
typedef __bf16 bf16x2 __attribute__((ext_vector_type(2)));
typedef float f32x4 __attribute__((ext_vector_type(4)));
typedef int i32x4 __attribute__((ext_vector_type(4)));

#define EDGE_DIM 64
#define NODE_DIM 128
#define XDIM 192     // agg(64) | nodes(128); globals folded into bias
#define HID_DIM 256
#define OUT_DIM 128
#define NBUCKET 512
#define NPB 98       // nodes per bucket: 512*98 = 50176 >= 50000; local < 128 (7 bits)
#define EPB 4096     // edges per hist/scatter block (256 thr x 16)
#define MT 64        // M-tile of fused MLP
#define HPAD 280     // Hs row stride (bf16)

// ---------------- K1: weight prep (+bias fold) + per-block bucket histogram --
__global__ __launch_bounds__(256) void prep_hist_kernel(
    const float* __restrict__ W1, const float* __restrict__ b1,
    const float* __restrict__ W2, const float* __restrict__ glob,
    __bf16* __restrict__ W1T, float* __restrict__ b1f, __bf16* __restrict__ W2T,
    const int* __restrict__ recv, int* __restrict__ bh, int n_edges) {
  const int b = blockIdx.x, t = threadIdx.x;
  if (b < HID_DIM) {
    if (t < XDIM) {
      W1T[b * XDIM + t] = (__bf16)W1[t * HID_DIM + b];
    } else {
      // threads 192..255 == wave 3: fold globals into bias (f32 exact)
      float p = glob[t - XDIM] * W1[t * HID_DIM + b];
      for (int off = 32; off; off >>= 1) p += __shfl_xor(p, off, 64);
      if (t == XDIM) b1f[b] = b1[b] + p;
    }
    return;
  }
  if (b < HID_DIM + OUT_DIM) {
    int nn = b - HID_DIM;
    W2T[nn * HID_DIM + t] = (__bf16)W2[t * OUT_DIM + nn];
    return;
  }
  const int hb = b - (HID_DIM + OUT_DIM);
  __shared__ int h[NBUCKET];
  for (int k = t; k < NBUCKET; k += 256) h[k] = 0;
  __syncthreads();
  const int i0 = hb * EPB + t * 16;
  if (i0 + 16 <= n_edges) {
#pragma unroll
    for (int c = 0; c < 4; ++c) {
      i32x4 r4 = *(const i32x4*)(recv + i0 + c * 4);
      atomicAdd(&h[r4.x / NPB], 1);
      atomicAdd(&h[r4.y / NPB], 1);
      atomicAdd(&h[r4.z / NPB], 1);
      atomicAdd(&h[r4.w / NPB], 1);
    }
  } else {
    for (int j = 0; j < 16; ++j)
      if (i0 + j < n_edges) atomicAdd(&h[recv[i0 + j] / NPB], 1);
  }
  __syncthreads();
  for (int k = t; k < NBUCKET; k += 256) bh[(size_t)hb * NBUCKET + k] = h[k];
}

// ---------------- K2a: WAVE-PARALLEL column scan (one wave per bucket) ------
__global__ __launch_bounds__(256) void col_scan_kernel(
    int* __restrict__ bh, int* __restrict__ tot, int nbh) {
  const int bucket = (blockIdx.x * 256 + threadIdx.x) >> 6;
  const int lane = threadIdx.x & 63;
  int running = 0;
  for (int c = 0; c < nbh; c += 64) {
    const int k = c + lane;
    int v = (k < nbh) ? bh[(size_t)k * NBUCKET + bucket] : 0;
    int incl = v;
    for (int off = 1; off < 64; off <<= 1) {
      int y = __shfl_up(incl, off, 64);
      if (lane >= off) incl += y;
    }
    if (k < nbh) bh[(size_t)k * NBUCKET + bucket] = running + incl - v;
    running += __shfl(incl, 63, 64);
  }
  if (lane == 0) tot[bucket] = running;
}

// ---------------- K2b: base scan over 512 totals (1 block) ------------------
__global__ __launch_bounds__(512) void base_scan_kernel(const int* __restrict__ tot,
                                                        int* __restrict__ base) {
  const int b = threadIdx.x;
  int v = tot[b];
  __shared__ int sums[NBUCKET];
  sums[b] = v;
  __syncthreads();
  for (int off = 1; off < NBUCKET; off <<= 1) {
    int y = (b >= off) ? sums[b - off] : 0;
    __syncthreads();
    sums[b] += y;
    __syncthreads();
  }
  base[b] = sums[b] - v;  // exclusive
  if (b == NBUCKET - 1) base[NBUCKET] = sums[b];
}

// ---------------- K3: scatter packed (eid<<7)|local, LDS cursors ------------
__global__ __launch_bounds__(256) void scatter_kernel(
    const int* __restrict__ recv, const int* __restrict__ off,
    const int* __restrict__ base, int* __restrict__ sorted1, int n_edges) {
  const int kb = blockIdx.x, t = threadIdx.x;
  __shared__ int cur[NBUCKET];
  for (int k = t; k < NBUCKET; k += 256)
    cur[k] = base[k] + off[(size_t)kb * NBUCKET + k];
  __syncthreads();
  const int i0 = kb * EPB + t * 16;
  if (i0 + 16 <= n_edges) {
#pragma unroll
    for (int c = 0; c < 4; ++c) {
      i32x4 r4 = *(const i32x4*)(recv + i0 + c * 4);
      const int e0 = i0 + c * 4;
      int bk, p;
      bk = r4.x / NPB; p = atomicAdd(&cur[bk], 1);
      sorted1[p] = ((e0 + 0) << 7) | (r4.x - bk * NPB);
      bk = r4.y / NPB; p = atomicAdd(&cur[bk], 1);
      sorted1[p] = ((e0 + 1) << 7) | (r4.y - bk * NPB);
      bk = r4.z / NPB; p = atomicAdd(&cur[bk], 1);
      sorted1[p] = ((e0 + 2) << 7) | (r4.z - bk * NPB);
      bk = r4.w / NPB; p = atomicAdd(&cur[bk], 1);
      sorted1[p] = ((e0 + 3) << 7) | (r4.w - bk * NPB);
    }
  } else {
    for (int j = 0; j < 16; ++j) {
      const int i = i0 + j;
      if (i < n_edges) {
        int r = recv[i];
        int bk = r / NPB;
        int p = atomicAdd(&cur[bk], 1);
        sorted1[p] = (i << 7) | (r - bk * NPB);
      }
    }
  }
}

// ---------------- K4: regroup bucket pairs -> per-node eid lists ------------
__global__ __launch_bounds__(256) void regroup_kernel(
    const int* __restrict__ sorted1, const int* __restrict__ base,
    int* __restrict__ nodeoff, int* __restrict__ ncount,
    int* __restrict__ eidcsr, int n_nodes) {
  const int b = blockIdx.x, t = threadIdx.x;
  __shared__ int cnt[NPB];
  __shared__ int loff[NPB];
  if (t < NPB) cnt[t] = 0;
  __syncthreads();
  const int s = base[b], e = base[b + 1];
  const int nb_ = b * NPB;
  for (int j = s + t; j < e; j += 256) atomicAdd(&cnt[sorted1[j] & 127], 1);
  __syncthreads();
  if (t == 0) {
    int run = 0;
#pragma unroll
    for (int k = 0; k < NPB; ++k) { loff[k] = run; run += cnt[k]; }
  }
  __syncthreads();
  if (t < NPB) {
    const int node = nb_ + t;
    if (node < n_nodes) { nodeoff[node] = s + loff[t]; ncount[node] = cnt[t]; }
    cnt[t] = 0;  // reuse as cursor
  }
  __syncthreads();
  for (int j = s + t; j < e; j += 256) {
    const int p = sorted1[j];
    const int local = p & 127;
    const int slot = atomicAdd(&cnt[local], 1);
    eidcsr[s + loff[local] + slot] = p >> 7;
  }
}

// ---------------- K5: build_x — proven quarter-wave f32x4 gather ------------
__global__ __launch_bounds__(256) void build_x_kernel(
    const float* __restrict__ edges, const int* __restrict__ nodeoff,
    const int* __restrict__ ncount, const int* __restrict__ eid,
    const float* __restrict__ nodes,
    __bf16* __restrict__ X, int n_nodes) {
  const int gwave = (blockIdx.x * 256 + threadIdx.x) >> 6;
  const int lane = threadIdx.x & 63;
  if (gwave >= n_nodes) return;
  const int q = lane >> 4;
  const int l15 = lane & 15;
  const int s = nodeoff[gwave];
  const int e = s + ncount[gwave];
  f32x4 a0 = {0.f, 0.f, 0.f, 0.f}, a1 = a0, a2 = a0, a3 = a0;

  int j = s + q;
  int i0 = (j < e) ? eid[j] : 0;
  int i1 = (j + 4 < e) ? eid[j + 4] : 0;
  int i2 = (j + 8 < e) ? eid[j + 8] : 0;
  int i3 = (j + 12 < e) ? eid[j + 12] : 0;

  while (j + 12 < e) {
    f32x4 v0 = __builtin_nontemporal_load((const f32x4*)(edges + (size_t)i0 * EDGE_DIM + l15 * 4));
    f32x4 v1 = __builtin_nontemporal_load((const f32x4*)(edges + (size_t)i1 * EDGE_DIM + l15 * 4));
    f32x4 v2 = __builtin_nontemporal_load((const f32x4*)(edges + (size_t)i2 * EDGE_DIM + l15 * 4));
    f32x4 v3 = __builtin_nontemporal_load((const f32x4*)(edges + (size_t)i3 * EDGE_DIM + l15 * 4));
    int n0 = (j + 16 < e) ? eid[j + 16] : 0;
    int n1 = (j + 20 < e) ? eid[j + 20] : 0;
    int n2 = (j + 24 < e) ? eid[j + 24] : 0;
    int n3 = (j + 28 < e) ? eid[j + 28] : 0;
    a0 += v0; a1 += v1; a2 += v2; a3 += v3;
    i0 = n0; i1 = n1; i2 = n2; i3 = n3;
    j += 16;
  }
  if (j < e)
    a0 += __builtin_nontemporal_load((const f32x4*)(edges + (size_t)i0 * EDGE_DIM + l15 * 4));
  if (j + 4 < e)
    a1 += __builtin_nontemporal_load((const f32x4*)(edges + (size_t)i1 * EDGE_DIM + l15 * 4));
  if (j + 8 < e)
    a2 += __builtin_nontemporal_load((const f32x4*)(edges + (size_t)i2 * EDGE_DIM + l15 * 4));

  a0 += a1; a2 += a3; a0 += a2;
#pragma unroll
  for (int c = 0; c < 4; ++c) {  // reduce across the 4 quarters
    float v = a0[c];
    v += __shfl_xor(v, 16, 64);
    v += __shfl_xor(v, 32, 64);
    a0[c] = v;
  }
  __bf16* row = X + (size_t)gwave * XDIM;
  if (q == 0) {
    bf16x4 o;
    o[0] = (__bf16)a0[0]; o[1] = (__bf16)a0[1];
    o[2] = (__bf16)a0[2]; o[3] = (__bf16)a0[3];
    *(bf16x4*)(row + l15 * 4) = o;  // 8B aligned store (row stride 384B)
  }
  float2 nv = *(const float2*)(nodes + (size_t)gwave * NODE_DIM + lane * 2);
  bf16x2 nb;
  nb[0] = (__bf16)nv.x; nb[1] = (__bf16)nv.y;
  *(bf16x2*)(row + EDGE_DIM + lane * 2) = nb;
}

// ---------------- K6: fused MLP (R15 structure, K=192 phase 1) --------------
__global__ __launch_bounds__(256, 2) void mlp_kernel(
    const __bf16* __restrict__ X, const __bf16* __restrict__ W1T,
    const float* __restrict__ b1f, const __bf16* __restrict__ W2T,
    const float* __restrict__ b2, float* __restrict__ out, int M) {
  __shared__ __bf16 Hs[MT][HPAD];
  const int wave = threadIdx.x >> 6;
  const int lane = threadIdx.x & 63;
  const int l15 = lane & 15;
  const int lk = lane >> 4;
  const int Mbase0 = blockIdx.x * MT;

  {  // phase 1: H = relu(X @ W1[:192] + b1') -> LDS  (K = 192, 6 ks steps)
    bf16x8 B1[4][6];
    float bias1[4];
    const int colbase = wave * 64;
#pragma unroll
    for (int cb = 0; cb < 4; ++cb) {
      const int col = colbase + cb * 16 + l15;
      const __bf16* wrow = W1T + col * XDIM + lk * 8;
#pragma unroll
      for (int ks = 0; ks < 6; ++ks) B1[cb][ks] = *(const bf16x8*)(wrow + ks * 32);
      bias1[cb] = b1f[col];
    }
#pragma unroll
    for (int mb = 0; mb < 4; ++mb) {
      const int Mbase = Mbase0 + mb * 16;
      f32x4 acc[4];
#pragma unroll
      for (int cb = 0; cb < 4; ++cb) {
        f32x4 ini = {bias1[cb], bias1[cb], bias1[cb], bias1[cb]};
        acc[cb] = ini;
      }
      const __bf16* xrow = X + (size_t)(Mbase + l15) * XDIM + lk * 8;
#pragma unroll
      for (int ks = 0; ks < 6; ++ks) {
        bf16x8 A = *(const bf16x8*)(xrow + ks * 32);
#pragma unroll
        for (int cb = 0; cb < 4; ++cb)
          acc[cb] = __builtin_amdgcn_mfma_f32_16x16x32_bf16(A, B1[cb][ks], acc[cb], 0, 0, 0);
      }
#pragma unroll
      for (int cb = 0; cb < 4; ++cb) {
#pragma unroll
        for (int r = 0; r < 4; ++r) {
          float v = acc[cb][r];
          Hs[mb * 16 + lk * 4 + r][colbase + cb * 16 + l15] = (__bf16)(v > 0.f ? v : 0.f);
        }
      }
    }
  }
  __syncthreads();
  {  // phase 2: out = H @ W2 + b2
    bf16x8 B2[2][8];
    float bias2[2];
    const int colbase = wave * 32;
#pragma unroll
    for (int cb = 0; cb < 2; ++cb) {
      const int col = colbase + cb * 16 + l15;
      const __bf16* wrow = W2T + col * HID_DIM + lk * 8;
#pragma unroll
      for (int ks = 0; ks < 8; ++ks) B2[cb][ks] = *(const bf16x8*)(wrow + ks * 32);
      bias2[cb] = b2[col];
    }
#pragma unroll
    for (int mb = 0; mb < 4; ++mb) {
      const int Mbase = Mbase0 + mb * 16;
      f32x4 acc[2];
#pragma unroll
      for (int cb = 0; cb < 2; ++cb) {
        f32x4 ini = {bias2[cb], bias2[cb], bias2[cb], bias2[cb]};
        acc[cb] = ini;
      }
#pragma unroll
      for (int ks = 0; ks < 8; ++ks) {
        bf16x8 A = *(const bf16x8*)(&Hs[mb * 16 + l15][lk * 8 + ks * 32]);
#pragma unroll
        for (int cb = 0; cb < 2; ++cb)
          acc[cb] = __builtin_amdgcn_mfma_f32_16x16x32_bf16(A, B2[cb][ks], acc[cb], 0, 0, 0);
      }
#pragma unroll
      for (int cb = 0; cb < 2; ++cb) {
        const int col = colbase + cb * 16 + l15;
#pragma unroll
        for (int r = 0; r < 4; ++r) {
          const int row = Mbase + lk * 4 + r;
          if (row < M) out[(size_t)row * OUT_DIM + col] = acc[cb][r];
        }
      }
    }
  }
}

extern "C" void kernel_launch(void* const* d_in, const int* in_sizes, int n_in,
                              void* d_out, int out_size, void* d_ws, size_t ws_size,
                              hipStream_t stream) {
  const float* edges    = (const float*)d_in[0];
  const int*   recv     = (const int*)d_in[1];
  const float* nodes    = (const float*)d_in[2];
  const float* globals_ = (const float*)d_in[3];
  const float* W1       = (const float*)d_in[5];
  const float* b1       = (const float*)d_in[6];
  const float* W2       = (const float*)d_in[7];
  const float* b2       = (const float*)d_in[8];

  const int n_edges = in_sizes[0] / EDGE_DIM;  // 1600000
  const int n_nodes = in_sizes[2] / NODE_DIM;  // 50000
  const int NBH = (n_edges + EPB - 1) / EPB;   // 391 hist/scatter blocks
  float* out = (float*)d_out;

  // workspace layout (~35 MB)
  char* ws = (char*)d_ws;
  size_t off = 0;
  int* bh = (int*)(ws + off);      off += (size_t)NBH * NBUCKET * 4;
  off = (off + 255) & ~(size_t)255;
  int* tot = (int*)(ws + off);     off += NBUCKET * 4;
  off = (off + 255) & ~(size_t)255;
  int* base = (int*)(ws + off);    off += (NBUCKET + 1) * 4;
  off = (off + 255) & ~(size_t)255;
  int* sorted1 = (int*)(ws + off); off += (size_t)n_edges * 4;
  off = (off + 255) & ~(size_t)255;
  int* nodeoff = (int*)(ws + off); off += (size_t)n_nodes * 4;
  off = (off + 255) & ~(size_t)255;
  int* ncount = (int*)(ws + off);  off += (size_t)n_nodes * 4;
  off = (off + 255) & ~(size_t)255;
  int* eidcsr = (int*)(ws + off);  off += (size_t)n_edges * 4;
  off = (off + 255) & ~(size_t)255;
  __bf16* X   = (__bf16*)(ws + off); off += (size_t)n_nodes * XDIM * 2;
  off = (off + 255) & ~(size_t)255;
  __bf16* W1T = (__bf16*)(ws + off); off += (size_t)HID_DIM * XDIM * 2;
  off = (off + 255) & ~(size_t)255;
  float* b1f = (float*)(ws + off);  off += HID_DIM * 4;
  off = (off + 255) & ~(size_t)255;
  __bf16* W2T = (__bf16*)(ws + off); off += (size_t)HID_DIM * OUT_DIM * 2;

  prep_hist_kernel<<<HID_DIM + OUT_DIM + NBH, 256, 0, stream>>>(
      W1, b1, W2, globals_, W1T, b1f, W2T, recv, bh, n_edges);
  col_scan_kernel<<<NBUCKET / 4, 256, 0, stream>>>(bh, tot, NBH);   // 512 waves
  base_scan_kernel<<<1, NBUCKET, 0, stream>>>(tot, base);
  scatter_kernel<<<NBH, 256, 0, stream>>>(recv, bh, base, sorted1, n_edges);
  regroup_kernel<<<NBUCKET, 256, 0, stream>>>(sorted1, base, nodeoff, ncount,
                                              eidcsr, n_nodes);
  build_x_kernel<<<(n_nodes + 3) / 4, 256, 0, stream>>>(edges, nodeoff, ncount, eidcsr,
                                                        nodes, X, n_nodes);
  mlp_kernel<<<(n_nodes + MT - 1) / MT, 256, 0, stream>>>(X, W1T, b1f, W2T, b2, out, n_nodes);
}

// Round 5
// 155.892 us; speedup vs baseline: 4.9564x; 1.0203x over previous
//
#include <hip/hip_runtime.h>

// NodeBlock: agg = segment_sum(edges[1.6M,64], recv -> 50000 nodes)
//            X = [agg | nodes] (globals folded into bias)  (50000 x 192) bf16
//            out = relu(X@W1[:192]+b1') @ W2 + b2          (f32, 50000 x 128)
//
// R24 = R23 (159.1 us) + fused front pipeline. Fixed-capacity buckets
// (CAP=4096 >= 17 sigma above the 3136 mean) make bucket bases b*CAP, so the
// hist->col_scan->base_scan chain is replaced by per-block global reservation
// (atomicAdd of the block's per-bucket counts). One kernel reads recv once,
// counts in LDS, reserves, scatters. Deletes col_scan/base_scan/bh and
// prep's recv pass (2 fewer launches, ~9 MB less traffic).
// R23 ledger: build_x 83 | mlp 31 | scatter+regroup 22 | small+gaps ~23.

typedef __bf16 bf16x8 __attribute__((ext_vector_type(8)));
typedef __bf16 bf16x4 __attribute__((ext_vector_type(4)));
typedef __bf16 bf16x2 __attribute__((ext_vector_type(2)));
typedef float f32x4 __attribute__((ext_vector_type(4)));
typedef int i32x4 __attribute__((ext_vector_type(4)));

#define EDGE_DIM 64
#define NODE_DIM 128
#define XDIM 192     // agg(64) | nodes(128); globals folded into bias
#define HID_DIM 256
#define OUT_DIM 128
#define NBUCKET 512
#define NPB 98       // nodes per bucket: 512*98 = 50176 >= 50000; local < 128 (7 bits)
#define CAP 4096     // bucket capacity (mean 3136, sigma ~56 -> 17 sigma margin)
#define EPB 4096     // edges per scatter block (256 thr x 16)
#define MT 64        // M-tile of MLP
#define HPAD 280     // Hs row stride (bf16)

// ---------------- K1: weight prep (+bias fold) + gcur init ------------------
__global__ __launch_bounds__(256) void prep_kernel(
    const float* __restrict__ W1, const float* __restrict__ b1,
    const float* __restrict__ W2, const float* __restrict__ glob,
    __bf16* __restrict__ W1T, float* __restrict__ b1f, __bf16* __restrict__ W2T,
    int* __restrict__ gcur) {
  const int b = blockIdx.x, t = threadIdx.x;
  if (b < HID_DIM) {
    if (t < XDIM) {
      W1T[b * XDIM + t] = (__bf16)W1[t * HID_DIM + b];
    } else {
      // threads 192..255 == wave 3: fold globals into bias (f32 exact)
      float p = glob[t - XDIM] * W1[t * HID_DIM + b];
      for (int off = 32; off; off >>= 1) p += __shfl_xor(p, off, 64);
      if (t == XDIM) b1f[b] = b1[b] + p;
    }
    return;
  }
  if (b < HID_DIM + OUT_DIM) {
    int nn = b - HID_DIM;
    W2T[nn * HID_DIM + t] = (__bf16)W2[t * OUT_DIM + nn];
    return;
  }
  // b == HID_DIM + OUT_DIM: init bucket cursors to fixed bases
  for (int k = t; k < NBUCKET; k += 256) gcur[k] = k * CAP;
}

// ---------------- K2: fused count + reserve + scatter -----------------------
__global__ __launch_bounds__(256) void scatter_kernel(
    const int* __restrict__ recv, int* __restrict__ gcur,
    int* __restrict__ sorted1, int n_edges) {
  const int kb = blockIdx.x, t = threadIdx.x;
  __shared__ int h[NBUCKET];  // pass 1: counts; pass 2: cursors
  for (int k = t; k < NBUCKET; k += 256) h[k] = 0;
  __syncthreads();

  const int i0 = kb * EPB + t * 16;
  int rr[16];
  int bk[16];
  if (i0 + 16 <= n_edges) {
#pragma unroll
    for (int c = 0; c < 4; ++c) {
      i32x4 r4 = *(const i32x4*)(recv + i0 + c * 4);
      rr[c * 4 + 0] = r4.x; rr[c * 4 + 1] = r4.y;
      rr[c * 4 + 2] = r4.z; rr[c * 4 + 3] = r4.w;
    }
  } else {
#pragma unroll
    for (int j = 0; j < 16; ++j) rr[j] = (i0 + j < n_edges) ? recv[i0 + j] : -1;
  }
#pragma unroll
  for (int j = 0; j < 16; ++j) {
    bk[j] = (rr[j] >= 0) ? (rr[j] / NPB) : -1;
    if (bk[j] >= 0) atomicAdd(&h[bk[j]], 1);
  }
  __syncthreads();

  // reserve this block's segment in each touched bucket (global atomic)
  for (int k = t; k < NBUCKET; k += 256) {
    int c = h[k];
    h[k] = (c > 0) ? atomicAdd(&gcur[k], c) : 0;  // overwrite count with base
  }
  __syncthreads();

  // scatter: cursor = LDS base, packed payload (eid<<7)|local
#pragma unroll
  for (int j = 0; j < 16; ++j) {
    if (bk[j] >= 0) {
      const int p = atomicAdd(&h[bk[j]], 1);
      sorted1[p] = ((i0 + j) << 7) | (rr[j] - bk[j] * NPB);
    }
  }
}

// ---------------- K3: regroup bucket -> per-node eid lists ------------------
__global__ __launch_bounds__(256) void regroup_kernel(
    const int* __restrict__ sorted1, const int* __restrict__ gcur,
    int* __restrict__ nodeoff, int* __restrict__ ncount,
    int* __restrict__ eidcsr, int n_nodes) {
  const int b = blockIdx.x, t = threadIdx.x;
  __shared__ int cnt[NPB];
  __shared__ int loff[NPB];
  if (t < NPB) cnt[t] = 0;
  __syncthreads();
  const int s = b * CAP, e = gcur[b];  // gcur now holds bucket end
  const int nb_ = b * NPB;
  for (int j = s + t; j < e; j += 256) atomicAdd(&cnt[sorted1[j] & 127], 1);
  __syncthreads();
  if (t == 0) {
    int run = 0;
#pragma unroll
    for (int k = 0; k < NPB; ++k) { loff[k] = run; run += cnt[k]; }
  }
  __syncthreads();
  if (t < NPB) {
    const int node = nb_ + t;
    if (node < n_nodes) { nodeoff[node] = s + loff[t]; ncount[node] = cnt[t]; }
    cnt[t] = 0;  // reuse as cursor
  }
  __syncthreads();
  for (int j = s + t; j < e; j += 256) {
    const int p = sorted1[j];
    const int local = p & 127;
    const int slot = atomicAdd(&cnt[local], 1);
    eidcsr[s + loff[local] + slot] = p >> 7;
  }
}

// ---------------- K4: build_x — proven quarter-wave f32x4 gather ------------
__global__ __launch_bounds__(256) void build_x_kernel(
    const float* __restrict__ edges, const int* __restrict__ nodeoff,
    const int* __restrict__ ncount, const int* __restrict__ eid,
    const float* __restrict__ nodes,
    __bf16* __restrict__ X, int n_nodes) {
  const int gwave = (blockIdx.x * 256 + threadIdx.x) >> 6;
  const int lane = threadIdx.x & 63;
  if (gwave >= n_nodes) return;
  const int q = lane >> 4;
  const int l15 = lane & 15;
  const int s = nodeoff[gwave];
  const int e = s + ncount[gwave];
  f32x4 a0 = {0.f, 0.f, 0.f, 0.f}, a1 = a0, a2 = a0, a3 = a0;

  int j = s + q;
  int i0 = (j < e) ? eid[j] : 0;
  int i1 = (j + 4 < e) ? eid[j + 4] : 0;
  int i2 = (j + 8 < e) ? eid[j + 8] : 0;
  int i3 = (j + 12 < e) ? eid[j + 12] : 0;

  while (j + 12 < e) {
    f32x4 v0 = __builtin_nontemporal_load((const f32x4*)(edges + (size_t)i0 * EDGE_DIM + l15 * 4));
    f32x4 v1 = __builtin_nontemporal_load((const f32x4*)(edges + (size_t)i1 * EDGE_DIM + l15 * 4));
    f32x4 v2 = __builtin_nontemporal_load((const f32x4*)(edges + (size_t)i2 * EDGE_DIM + l15 * 4));
    f32x4 v3 = __builtin_nontemporal_load((const f32x4*)(edges + (size_t)i3 * EDGE_DIM + l15 * 4));
    int n0 = (j + 16 < e) ? eid[j + 16] : 0;
    int n1 = (j + 20 < e) ? eid[j + 20] : 0;
    int n2 = (j + 24 < e) ? eid[j + 24] : 0;
    int n3 = (j + 28 < e) ? eid[j + 28] : 0;
    a0 += v0; a1 += v1; a2 += v2; a3 += v3;
    i0 = n0; i1 = n1; i2 = n2; i3 = n3;
    j += 16;
  }
  if (j < e)
    a0 += __builtin_nontemporal_load((const f32x4*)(edges + (size_t)i0 * EDGE_DIM + l15 * 4));
  if (j + 4 < e)
    a1 += __builtin_nontemporal_load((const f32x4*)(edges + (size_t)i1 * EDGE_DIM + l15 * 4));
  if (j + 8 < e)
    a2 += __builtin_nontemporal_load((const f32x4*)(edges + (size_t)i2 * EDGE_DIM + l15 * 4));

  a0 += a1; a2 += a3; a0 += a2;
#pragma unroll
  for (int c = 0; c < 4; ++c) {  // reduce across the 4 quarters
    float v = a0[c];
    v += __shfl_xor(v, 16, 64);
    v += __shfl_xor(v, 32, 64);
    a0[c] = v;
  }
  __bf16* row = X + (size_t)gwave * XDIM;
  if (q == 0) {
    bf16x4 o;
    o[0] = (__bf16)a0[0]; o[1] = (__bf16)a0[1];
    o[2] = (__bf16)a0[2]; o[3] = (__bf16)a0[3];
    *(bf16x4*)(row + l15 * 4) = o;  // 8B aligned store (row stride 384B)
  }
  float2 nv = *(const float2*)(nodes + (size_t)gwave * NODE_DIM + lane * 2);
  bf16x2 nb;
  nb[0] = (__bf16)nv.x; nb[1] = (__bf16)nv.y;
  *(bf16x2*)(row + EDGE_DIM + lane * 2) = nb;
}

// ---------------- K5: fused MLP (R15 structure, K=192 phase 1) --------------
__global__ __launch_bounds__(256, 2) void mlp_kernel(
    const __bf16* __restrict__ X, const __bf16* __restrict__ W1T,
    const float* __restrict__ b1f, const __bf16* __restrict__ W2T,
    const float* __restrict__ b2, float* __restrict__ out, int M) {
  __shared__ __bf16 Hs[MT][HPAD];
  const int wave = threadIdx.x >> 6;
  const int lane = threadIdx.x & 63;
  const int l15 = lane & 15;
  const int lk = lane >> 4;
  const int Mbase0 = blockIdx.x * MT;

  {  // phase 1: H = relu(X @ W1[:192] + b1') -> LDS  (K = 192, 6 ks steps)
    bf16x8 B1[4][6];
    float bias1[4];
    const int colbase = wave * 64;
#pragma unroll
    for (int cb = 0; cb < 4; ++cb) {
      const int col = colbase + cb * 16 + l15;
      const __bf16* wrow = W1T + col * XDIM + lk * 8;
#pragma unroll
      for (int ks = 0; ks < 6; ++ks) B1[cb][ks] = *(const bf16x8*)(wrow + ks * 32);
      bias1[cb] = b1f[col];
    }
#pragma unroll
    for (int mb = 0; mb < 4; ++mb) {
      const int Mbase = Mbase0 + mb * 16;
      f32x4 acc[4];
#pragma unroll
      for (int cb = 0; cb < 4; ++cb) {
        f32x4 ini = {bias1[cb], bias1[cb], bias1[cb], bias1[cb]};
        acc[cb] = ini;
      }
      const __bf16* xrow = X + (size_t)(Mbase + l15) * XDIM + lk * 8;
#pragma unroll
      for (int ks = 0; ks < 6; ++ks) {
        bf16x8 A = *(const bf16x8*)(xrow + ks * 32);
#pragma unroll
        for (int cb = 0; cb < 4; ++cb)
          acc[cb] = __builtin_amdgcn_mfma_f32_16x16x32_bf16(A, B1[cb][ks], acc[cb], 0, 0, 0);
      }
#pragma unroll
      for (int cb = 0; cb < 4; ++cb) {
#pragma unroll
        for (int r = 0; r < 4; ++r) {
          float v = acc[cb][r];
          Hs[mb * 16 + lk * 4 + r][colbase + cb * 16 + l15] = (__bf16)(v > 0.f ? v : 0.f);
        }
      }
    }
  }
  __syncthreads();
  {  // phase 2: out = H @ W2 + b2
    bf16x8 B2[2][8];
    float bias2[2];
    const int colbase = wave * 32;
#pragma unroll
    for (int cb = 0; cb < 2; ++cb) {
      const int col = colbase + cb * 16 + l15;
      const __bf16* wrow = W2T + col * HID_DIM + lk * 8;
#pragma unroll
      for (int ks = 0; ks < 8; ++ks) B2[cb][ks] = *(const bf16x8*)(wrow + ks * 32);
      bias2[cb] = b2[col];
    }
#pragma unroll
    for (int mb = 0; mb < 4; ++mb) {
      const int Mbase = Mbase0 + mb * 16;
      f32x4 acc[2];
#pragma unroll
      for (int cb = 0; cb < 2; ++cb) {
        f32x4 ini = {bias2[cb], bias2[cb], bias2[cb], bias2[cb]};
        acc[cb] = ini;
      }
#pragma unroll
      for (int ks = 0; ks < 8; ++ks) {
        bf16x8 A = *(const bf16x8*)(&Hs[mb * 16 + l15][lk * 8 + ks * 32]);
#pragma unroll
        for (int cb = 0; cb < 2; ++cb)
          acc[cb] = __builtin_amdgcn_mfma_f32_16x16x32_bf16(A, B2[cb][ks], acc[cb], 0, 0, 0);
      }
#pragma unroll
      for (int cb = 0; cb < 2; ++cb) {
        const int col = colbase + cb * 16 + l15;
#pragma unroll
        for (int r = 0; r < 4; ++r) {
          const int row = Mbase + lk * 4 + r;
          if (row < M) out[(size_t)row * OUT_DIM + col] = acc[cb][r];
        }
      }
    }
  }
}

extern "C" void kernel_launch(void* const* d_in, const int* in_sizes, int n_in,
                              void* d_out, int out_size, void* d_ws, size_t ws_size,
                              hipStream_t stream) {
  const float* edges    = (const float*)d_in[0];
  const int*   recv     = (const int*)d_in[1];
  const float* nodes    = (const float*)d_in[2];
  const float* globals_ = (const float*)d_in[3];
  const float* W1       = (const float*)d_in[5];
  const float* b1       = (const float*)d_in[6];
  const float* W2       = (const float*)d_in[7];
  const float* b2       = (const float*)d_in[8];

  const int n_edges = in_sizes[0] / EDGE_DIM;  // 1600000
  const int n_nodes = in_sizes[2] / NODE_DIM;  // 50000
  const int NBH = (n_edges + EPB - 1) / EPB;   // 391 scatter blocks
  float* out = (float*)d_out;

  // workspace layout (~37 MB)
  char* ws = (char*)d_ws;
  size_t off = 0;
  int* gcur = (int*)(ws + off);    off += NBUCKET * 4;
  off = (off + 255) & ~(size_t)255;
  int* sorted1 = (int*)(ws + off); off += (size_t)NBUCKET * CAP * 4;  // 8 MB
  off = (off + 255) & ~(size_t)255;
  int* nodeoff = (int*)(ws + off); off += (size_t)n_nodes * 4;
  off = (off + 255) & ~(size_t)255;
  int* ncount = (int*)(ws + off);  off += (size_t)n_nodes * 4;
  off = (off + 255) & ~(size_t)255;
  int* eidcsr = (int*)(ws + off);  off += (size_t)NBUCKET * CAP * 4;  // 8 MB
  off = (off + 255) & ~(size_t)255;
  __bf16* X   = (__bf16*)(ws + off); off += (size_t)n_nodes * XDIM * 2;
  off = (off + 255) & ~(size_t)255;
  __bf16* W1T = (__bf16*)(ws + off); off += (size_t)HID_DIM * XDIM * 2;
  off = (off + 255) & ~(size_t)255;
  float* b1f = (float*)(ws + off);  off += HID_DIM * 4;
  off = (off + 255) & ~(size_t)255;
  __bf16* W2T = (__bf16*)(ws + off); off += (size_t)HID_DIM * OUT_DIM * 2;

  prep_kernel<<<HID_DIM + OUT_DIM + 1, 256, 0, stream>>>(
      W1, b1, W2, globals_, W1T, b1f, W2T, gcur);
  scatter_kernel<<<NBH, 256, 0, stream>>>(recv, gcur, sorted1, n_edges);
  regroup_kernel<<<NBUCKET, 256, 0, stream>>>(sorted1, gcur, nodeoff, ncount,
                                              eidcsr, n_nodes);
  build_x_kernel<<<(n_nodes + 3) / 4, 256, 0, stream>>>(edges, nodeoff, ncount, eidcsr,
                                                        nodes, X, n_nodes);
  mlp_kernel<<<(n_nodes + MT - 1) / MT, 256, 0, stream>>>(X, W1T, b1f, W2T, b2, out, n_nodes);
}